// Round 1
// baseline (23543.839 us; speedup 1.0000x reference)
//
#include <hip/hip_runtime.h>
#include <math.h>

#define NB   16
#define NN   16384
#define LDIM 512
#define DDIM 128
#define HIDD 128
#define NCLS 3
#define KCAP 256
#define EPSV 1e-8f

__device__ __forceinline__ int get_k(const int* kp) {
    int k = kp[0];
    if (k < 1 || k > NN) {
        float f = __int_as_float(k);
        if (f >= 1.0f && f <= (float)NN) k = (int)f;
        else k = 70;
    }
    if (k > NN) k = NN;
    return k;
}

// order-preserving uint key for float compare
__device__ __forceinline__ unsigned okey(float f) {
    unsigned u = __float_as_uint(f);
    return (u & 0x80000000u) ? ~u : (u | 0x80000000u);
}

// ---------------------------------------------------------------------------
// K1: fused gated-attention logits.
// logits[row] = sum_d tanh(x_row.Wv_d + bv_d)*sigmoid(x_row.Wu_d + bu_d)*Wa_d + ba
// Block: 256 threads, 64 rows/block, l-tile 32.
// thread t -> d = t&127 (column), g = t>>7 (row half: 32 rows each).
// LDS: Wv tile 16KB + Wu tile 16KB + x tile 8KB = 40KB -> 4 blocks/CU.
// ---------------------------------------------------------------------------
__global__ __launch_bounds__(256, 4)
void k1_logits(const float* __restrict__ x,
               const float* __restrict__ Wv, const float* __restrict__ bv,
               const float* __restrict__ Wu, const float* __restrict__ bu,
               const float* __restrict__ Wa, const float* __restrict__ ba,
               float* __restrict__ logits)
{
    __shared__ __align__(16) float sWv[32 * 128];
    __shared__ __align__(16) float sWu[32 * 128];
    __shared__ __align__(16) float sX[64 * 32];

    const int t    = threadIdx.x;
    const int row0 = blockIdx.x * 64;
    const int d    = t & 127;
    const int g    = t >> 7;   // row group 0/1
    const int w    = t >> 6;   // wave id 0..3

    float accV[32], accU[32];
#pragma unroll
    for (int r = 0; r < 32; ++r) { accV[r] = 0.0f; accU[r] = 0.0f; }

    for (int lt = 0; lt < LDIM; lt += 32) {
        // stage W tiles: 32x128 floats = 1024 float4 each
        const float4* gWv = reinterpret_cast<const float4*>(Wv + (size_t)lt * 128);
        const float4* gWu = reinterpret_cast<const float4*>(Wu + (size_t)lt * 128);
        float4* s4v = reinterpret_cast<float4*>(sWv);
        float4* s4u = reinterpret_cast<float4*>(sWu);
#pragma unroll
        for (int i = 0; i < 4; ++i) {
            s4v[t + i * 256] = gWv[t + i * 256];
            s4u[t + i * 256] = gWu[t + i * 256];
        }
        // stage x tile: 64 rows x 32 cols = 512 float4
        float4* s4x = reinterpret_cast<float4*>(sX);
#pragma unroll
        for (int i = 0; i < 2; ++i) {
            int f = t + i * 256;
            int r = f >> 3;      // row in tile
            int j = f & 7;       // float4 within row
            s4x[f] = *reinterpret_cast<const float4*>(
                x + (size_t)(row0 + r) * LDIM + lt + j * 4);
        }
        __syncthreads();

        const float4* sxf4 = reinterpret_cast<const float4*>(sX);
#pragma unroll
        for (int l4 = 0; l4 < 8; ++l4) {
            float wv0 = sWv[(l4 * 4 + 0) * 128 + d];
            float wv1 = sWv[(l4 * 4 + 1) * 128 + d];
            float wv2 = sWv[(l4 * 4 + 2) * 128 + d];
            float wv3 = sWv[(l4 * 4 + 3) * 128 + d];
            float wu0 = sWu[(l4 * 4 + 0) * 128 + d];
            float wu1 = sWu[(l4 * 4 + 1) * 128 + d];
            float wu2 = sWu[(l4 * 4 + 2) * 128 + d];
            float wu3 = sWu[(l4 * 4 + 3) * 128 + d];
#pragma unroll
            for (int r = 0; r < 32; ++r) {
                float4 xv = sxf4[(g * 32 + r) * 8 + l4];  // wave-uniform: LDS broadcast
                accV[r] = fmaf(xv.x, wv0, accV[r]);
                accV[r] = fmaf(xv.y, wv1, accV[r]);
                accV[r] = fmaf(xv.z, wv2, accV[r]);
                accV[r] = fmaf(xv.w, wv3, accV[r]);
                accU[r] = fmaf(xv.x, wu0, accU[r]);
                accU[r] = fmaf(xv.y, wu1, accU[r]);
                accU[r] = fmaf(xv.z, wu2, accU[r]);
                accU[r] = fmaf(xv.w, wu3, accU[r]);
            }
        }
        __syncthreads();
    }

    // epilogue: tanh * sigmoid * Wa, reduce across the 128 d-threads (2 waves)
    const float bvd = bv[d], bud = bu[d], wad = Wa[d];
    float red[32];
#pragma unroll
    for (int r = 0; r < 32; ++r) {
        float v = tanhf(accV[r] + bvd);
        float s = 1.0f / (1.0f + expf(-(accU[r] + bud)));
        float c = v * s * wad;
#pragma unroll
        for (int m2 = 1; m2 < 64; m2 <<= 1) c += __shfl_xor(c, m2);
        red[r] = c;
    }
    float (*sRed)[32] = reinterpret_cast<float(*)[32]>(sX);  // alias, safe after sync
    if ((t & 63) == 0) {
#pragma unroll
        for (int r = 0; r < 32; ++r) sRed[w][r] = red[r];
    }
    __syncthreads();
    if (t < 64) {
        float sv = (t < 32) ? (sRed[0][t] + sRed[1][t])
                            : (sRed[2][t - 32] + sRed[3][t - 32]);
        logits[row0 + t] = sv + ba[0];
    }
}

// ---------------------------------------------------------------------------
// K2: per-batch softmax over N, * mask, renormalize. In-place on A (logits in).
// ---------------------------------------------------------------------------
__global__ void k2_softmax(float* __restrict__ A, const float* __restrict__ mask)
{
    __shared__ float sred[4];
    const int b = blockIdx.x;
    const int t = threadIdx.x;
    const int w = t >> 6;
    float* Ab = A + (size_t)b * NN;
    const float* mb = mask + (size_t)b * NN;

    // pass 1: max
    float mx = -INFINITY;
    for (int i = t; i < NN; i += 256) mx = fmaxf(mx, Ab[i]);
#pragma unroll
    for (int m2 = 1; m2 < 64; m2 <<= 1) mx = fmaxf(mx, __shfl_xor(mx, m2));
    if ((t & 63) == 0) sred[w] = mx;
    __syncthreads();
    mx = fmaxf(fmaxf(sred[0], sred[1]), fmaxf(sred[2], sred[3]));
    __syncthreads();

    // pass 2: sum of exp
    float se = 0.0f;
    for (int i = t; i < NN; i += 256) se += expf(Ab[i] - mx);
#pragma unroll
    for (int m2 = 1; m2 < 64; m2 <<= 1) se += __shfl_xor(se, m2);
    if ((t & 63) == 0) sred[w] = se;
    __syncthreads();
    float sum_e = sred[0] + sred[1] + sred[2] + sred[3];
    __syncthreads();

    // pass 3: P = e/sum * mask, write; accumulate S2
    float inv_se = 1.0f / sum_e;
    float s2 = 0.0f;
    for (int i = t; i < NN; i += 256) {
        float p = expf(Ab[i] - mx) * inv_se * mb[i];
        Ab[i] = p;
        s2 += p;
    }
#pragma unroll
    for (int m2 = 1; m2 < 64; m2 <<= 1) s2 += __shfl_xor(s2, m2);
    if ((t & 63) == 0) sred[w] = s2;
    __syncthreads();
    float S2 = sred[0] + sred[1] + sred[2] + sred[3];

    // pass 4: renormalize
    float scale = 1.0f / (S2 + EPSV);
    for (int i = t; i < NN; i += 256) Ab[i] *= scale;
}

// ---------------------------------------------------------------------------
// K3: exact top-k per batch via binary search on ordered-uint keys (cached in
// registers), tie-break at the k-th value by lowest index (matches lax.top_k
// set semantics). Output: sorted-ascending index list (deterministic).
// ---------------------------------------------------------------------------
__global__ void k3_topk(const float* __restrict__ A, const int* __restrict__ kp,
                        int* __restrict__ outIdx)
{
    __shared__ int sredi[4];
    __shared__ int sCntG, sCntE;
    __shared__ int sIdx[KCAP];
    __shared__ int sEq[512];
    const int b = blockIdx.x;
    const int t = threadIdx.x;
    const int w = t >> 6;
    int k = get_k(kp); if (k > KCAP) k = KCAP;
    const float* Ab = A + (size_t)b * NN;

    unsigned kk[64];
#pragma unroll
    for (int j = 0; j < 64; ++j) kk[j] = okey(Ab[t + j * 256]);

    // find T = k-th largest key: largest T with count(key >= T) >= k
    unsigned lo = 0u, hi = 0xFFFFFFFFu;
    while (lo < hi) {
        unsigned span = hi - lo;
        unsigned mid = lo + (span >> 1) + (span & 1u);  // ceil midpoint, no overflow
        int c = 0;
#pragma unroll
        for (int j = 0; j < 64; ++j) c += (kk[j] >= mid) ? 1 : 0;
#pragma unroll
        for (int m2 = 1; m2 < 64; m2 <<= 1) c += __shfl_xor(c, m2);
        __syncthreads();
        if ((t & 63) == 0) sredi[w] = c;
        __syncthreads();
        c = sredi[0] + sredi[1] + sredi[2] + sredi[3];
        if (c >= k) lo = mid; else hi = mid - 1;
    }
    const unsigned T = lo;

    if (t == 0) { sCntG = 0; sCntE = 0; }
    __syncthreads();
#pragma unroll
    for (int j = 0; j < 64; ++j) {
        unsigned ky = kk[j];
        int i = t + j * 256;
        if (ky > T)       { int p = atomicAdd(&sCntG, 1); if (p < KCAP) sIdx[p] = i; }
        else if (ky == T) { int p = atomicAdd(&sCntE, 1); if (p < 512)  sEq[p]  = i; }
    }
    __syncthreads();
    if (t == 0) {
        int m = sCntG; if (m > k) m = k;   // count(>T) < k guaranteed by search
        int need = k - m;
        int ec = sCntE; if (ec > 512) ec = 512;
        for (int j2 = 0; j2 < need; ++j2) {         // usually need == 1, ec == 1
            int bi = 0x7FFFFFFF, be = -1;
            for (int e = 0; e < ec; ++e) { int vv = sEq[e]; if (vv < bi) { bi = vv; be = e; } }
            if (be >= 0) { sEq[be] = 0x7FFFFFFF; sIdx[m + j2] = bi; }
            else sIdx[m + j2] = 0;
        }
    }
    __syncthreads();
    // parallel rank sort (indices distinct -> ranks unique) -> deterministic order
    if (t < k) {
        int myv = sIdx[t];
        int rank = 0;
        for (int e = 0; e < k; ++e) rank += (sIdx[e] < myv) ? 1 : 0;
        outIdx[b * KCAP + rank] = myv;
    }
}

// ---------------------------------------------------------------------------
// K4: gather top-k rows of x, mean-pool, MLP (relu(pooled@W1+b1)@W2+b2),
// argmax. One block per batch.
// ---------------------------------------------------------------------------
__global__ void k4_final(const float* __restrict__ x, const int* __restrict__ idxws,
                         const int* __restrict__ kp,
                         const float* __restrict__ W1, const float* __restrict__ b1,
                         const float* __restrict__ W2, const float* __restrict__ b2,
                         float* __restrict__ Yprob, float* __restrict__ Yhat)
{
    __shared__ float sPooled[LDIM];
    __shared__ float sH[HIDD];
    __shared__ float sY[4];
    __shared__ int   sIdx[KCAP];
    const int b = blockIdx.x;
    const int t = threadIdx.x;
    int k = get_k(kp); if (k > KCAP) k = KCAP;

    if (t < k) sIdx[t] = idxws[b * KCAP + t];
    __syncthreads();

    float a0 = 0.0f, a1 = 0.0f;
    for (int j = 0; j < k; ++j) {
        const float* xr = x + ((size_t)b * NN + (size_t)sIdx[j]) * LDIM;
        a0 += xr[t];
        a1 += xr[t + 256];
    }
    const float invk = 1.0f / (float)k;
    sPooled[t]       = a0 * invk;
    sPooled[t + 256] = a1 * invk;
    __syncthreads();

    if (t < HIDD) {
        float acc = b1[t];
        for (int l = 0; l < LDIM; ++l) acc = fmaf(sPooled[l], W1[l * HIDD + t], acc);
        sH[t] = fmaxf(acc, 0.0f);
    }
    __syncthreads();
    if (t < NCLS) {
        float y = b2[t];
        for (int h = 0; h < HIDD; ++h) y = fmaf(sH[h], W2[h * NCLS + t], y);
        Yprob[b * NCLS + t] = y;
        sY[t] = y;
    }
    __syncthreads();
    if (t == 0) {
        int am = 0; float bst = sY[0];
        if (sY[1] > bst) { bst = sY[1]; am = 1; }
        if (sY[2] > bst) { bst = sY[2]; am = 2; }
        Yhat[b] = (float)am;   // argmax, first-max tie-break
    }
}

// ---------------------------------------------------------------------------
extern "C" void kernel_launch(void* const* d_in, const int* in_sizes, int n_in,
                              void* d_out, int out_size, void* d_ws, size_t ws_size,
                              hipStream_t stream)
{
    const float* x    = (const float*)d_in[0];
    const float* mask = (const float*)d_in[1];
    const float* Wv   = (const float*)d_in[2];
    const float* bv   = (const float*)d_in[3];
    const float* Wu   = (const float*)d_in[4];
    const float* bu   = (const float*)d_in[5];
    const float* Wa   = (const float*)d_in[6];
    const float* ba   = (const float*)d_in[7];
    const float* W1   = (const float*)d_in[8];
    const float* b1   = (const float*)d_in[9];
    const float* W2   = (const float*)d_in[10];
    const float* b2   = (const float*)d_in[11];
    const int*   kp   = (const int*)d_in[12];

    float* out   = (float*)d_out;
    float* Yprob = out;        // [16,3] = 48
    float* Yhat  = out + 48;   // [16]
    float* A     = out + 64;   // [16,16384]

    int* idxws = (int*)d_ws;   // 16 * KCAP ints

    k1_logits<<<dim3((NB * NN) / 64), dim3(256), 0, stream>>>(
        x, Wv, bv, Wu, bu, Wa, ba, A);
    k2_softmax<<<dim3(NB), dim3(256), 0, stream>>>(A, mask);
    k3_topk<<<dim3(NB), dim3(256), 0, stream>>>(A, kp, idxws);
    k4_final<<<dim3(NB), dim3(256), 0, stream>>>(
        x, idxws, kp, W1, b1, W2, b2, Yprob, Yhat);
}

// Round 2
// 462.845 us; speedup vs baseline: 50.8676x; 50.8676x over previous
//
#include <hip/hip_runtime.h>
#include <math.h>

#define NB   16
#define NN   16384
#define LDIM 512
#define DDIM 128
#define HIDD 128
#define NCLS 3
#define KCAP 256
#define CCAP 1024
#define EPSV 1e-8f
#define DELTA 0.02f

typedef float  f32x4  __attribute__((ext_vector_type(4)));
typedef int    i32x4  __attribute__((ext_vector_type(4)));
typedef __bf16 bf16x8 __attribute__((ext_vector_type(8)));

static_assert(sizeof(bf16x8) == 16, "frag size");
static_assert(sizeof(i32x4) == 16, "frag size");

__device__ __forceinline__ int get_k(const int* kp) {
    int k = kp[0];
    if (k < 1 || k > NN) {
        float f = __int_as_float(k);
        if (f >= 1.0f && f <= (float)NN) k = (int)f;
        else k = 70;
    }
    if (k > NN) k = NN;
    return k;
}

// order-preserving uint key for float compare
__device__ __forceinline__ unsigned okey(float f) {
    unsigned u = __float_as_uint(f);
    return (u & 0x80000000u) ? ~u : (u | 0x80000000u);
}
__device__ __forceinline__ float inv_okey(unsigned k) {
    unsigned u = (k & 0x80000000u) ? (k & 0x7FFFFFFFu) : ~k;
    return __uint_as_float(u);
}

// pack two fp32 -> two RNE bf16 in one u32 (a -> low, b -> high)
__device__ __forceinline__ unsigned pk2bf(float a, float b) {
    unsigned ua = __float_as_uint(a); ua = (ua + 0x7FFFu + ((ua >> 16) & 1u)) >> 16;
    unsigned ub = __float_as_uint(b); ub = (ub + 0x7FFFu + ((ub >> 16) & 1u)) & 0xFFFF0000u;
    return (ua & 0xFFFFu) | ub;
}

__device__ __forceinline__ f32x4 mfma16(i32x4 a, i32x4 b, f32x4 c) {
    return __builtin_amdgcn_mfma_f32_16x16x32_bf16(
        __builtin_bit_cast(bf16x8, a), __builtin_bit_cast(bf16x8, b), c, 0, 0, 0);
}

__device__ __forceinline__ float sig_fast(float v)  { return 1.0f / (1.0f + __expf(-v)); }
__device__ __forceinline__ float tanh_fast(float v) { return 1.0f - 2.0f / (1.0f + __expf(2.0f * v)); }

// ---------------------------------------------------------------------------
// K0: swizzle Wv,Wu (fp32 [512][128]) into bf16 fragment order:
// Wp[g][kt][n][ks]  (g in {V,U}, kt=k/32, n=col, ks=k%32), flat stride:
// g*65536 + kt*4096 + n*32 + ks.
// ---------------------------------------------------------------------------
__global__ void k0_prep(const float* __restrict__ Wv, const float* __restrict__ Wu,
                        unsigned short* __restrict__ Wp)
{
    int i = blockIdx.x * 256 + threadIdx.x;    // 0 .. 131071
    int g   = i >> 16;
    int rem = i & 65535;                       // kdim*128 + n
    int kd  = rem >> 7;
    int n   = rem & 127;
    float w = g ? Wu[rem] : Wv[rem];
    unsigned u = __float_as_uint(w);
    u = (u + 0x7FFFu + ((u >> 16) & 1u)) >> 16;
    Wp[(size_t)g * 65536 + (size_t)(kd >> 5) * 4096 + n * 32 + (kd & 31)] = (unsigned short)u;
}

// ---------------------------------------------------------------------------
// K1: fused gated-attention logits via bf16 MFMA. No LDS, no barriers.
// Block 256 thr = 4 waves; wave owns 32 rows x 128 cols x both gates.
// acc[gate][rowtile][ntile] : 2*2*8 f32x4 = 128 VGPRs.
// A frag: lane l -> row (l&15), k = (l>>4)*8 + j (8 consecutive fp32 -> bf16).
// B frag: lane l -> col (l&15), k = (l>>4)*8 + j (pre-swizzled, one dwordx4).
// D frag: reg r -> row (l>>4)*4 + r, col (l&15).
// ---------------------------------------------------------------------------
__global__ __launch_bounds__(256)
void k1_mfma(const float* __restrict__ x, const unsigned short* __restrict__ Wp,
             const float* __restrict__ bv, const float* __restrict__ bu,
             const float* __restrict__ Wa, const float* __restrict__ ba,
             float* __restrict__ logits)
{
    const int t   = threadIdx.x;
    const int wid = t >> 6;
    const int l   = t & 63;
    const int lr  = l & 15;
    const int lg  = l >> 4;
    const int row0w = blockIdx.x * 128 + wid * 32;

    f32x4 acc[2][2][8];
#pragma unroll
    for (int g = 0; g < 2; ++g)
#pragma unroll
        for (int rt = 0; rt < 2; ++rt)
#pragma unroll
            for (int nt = 0; nt < 8; ++nt)
                acc[g][rt][nt] = f32x4{0.f, 0.f, 0.f, 0.f};

    const float* xp0 = x + (size_t)(row0w + lr) * LDIM + lg * 8;
    const float* xp1 = xp0 + 16 * LDIM;
    const int wlane = lr * 32 + lg * 8;

    f32x4 ca0 = ((const f32x4*)xp0)[0];
    f32x4 cb0 = ((const f32x4*)xp0)[1];
    f32x4 ca1 = ((const f32x4*)xp1)[0];
    f32x4 cb1 = ((const f32x4*)xp1)[1];

#pragma unroll 2
    for (int kt = 0; kt < 16; ++kt) {
        f32x4 na0 = ca0, nb0 = cb0, na1 = ca1, nb1 = cb1;
        if (kt < 15) {                       // prefetch next K-slice (issue-early)
            const float* q0 = xp0 + (size_t)(kt + 1) * 32;
            const float* q1 = xp1 + (size_t)(kt + 1) * 32;
            na0 = ((const f32x4*)q0)[0]; nb0 = ((const f32x4*)q0)[1];
            na1 = ((const f32x4*)q1)[0]; nb1 = ((const f32x4*)q1)[1];
        }
        i32x4 a0, a1;
        a0.x = pk2bf(ca0.x, ca0.y); a0.y = pk2bf(ca0.z, ca0.w);
        a0.z = pk2bf(cb0.x, cb0.y); a0.w = pk2bf(cb0.z, cb0.w);
        a1.x = pk2bf(ca1.x, ca1.y); a1.y = pk2bf(ca1.z, ca1.w);
        a1.z = pk2bf(cb1.x, cb1.y); a1.w = pk2bf(cb1.z, cb1.w);

        const unsigned short* wk = Wp + (size_t)kt * 4096 + wlane;
#pragma unroll
        for (int g = 0; g < 2; ++g) {
#pragma unroll
            for (int nt = 0; nt < 8; ++nt) {
                i32x4 bf = *(const i32x4*)(wk + g * 65536 + nt * 512);
                acc[g][0][nt] = mfma16(a0, bf, acc[g][0][nt]);
                acc[g][1][nt] = mfma16(a1, bf, acc[g][1][nt]);
            }
        }
        ca0 = na0; cb0 = nb0; ca1 = na1; cb1 = nb1;
    }

    // epilogue: tanh(V+bv)*sigmoid(U+bu)*Wa, reduce over the 128 cols
    float bvc[8], buc[8], wac[8];
#pragma unroll
    for (int nt = 0; nt < 8; ++nt) {
        int col = nt * 16 + lr;
        bvc[nt] = bv[col]; buc[nt] = bu[col]; wac[nt] = Wa[col];
    }
    const float ba0 = ba[0];
#pragma unroll
    for (int rt = 0; rt < 2; ++rt) {
#pragma unroll
        for (int r = 0; r < 4; ++r) {
            float s = 0.f;
#pragma unroll
            for (int nt = 0; nt < 8; ++nt) {
                float vv = tanh_fast(acc[0][rt][nt][r] + bvc[nt]);
                float uu = sig_fast (acc[1][rt][nt][r] + buc[nt]);
                s = fmaf(vv * uu, wac[nt], s);
            }
            // sum over lr (16-lane groups share lg)
            s += __shfl_xor(s, 1); s += __shfl_xor(s, 2);
            s += __shfl_xor(s, 4); s += __shfl_xor(s, 8);
            if (lr == 0)
                logits[row0w + rt * 16 + lg * 4 + r] = s + ba0;
        }
    }
}

// ---------------------------------------------------------------------------
// K2: per-batch softmax over N, * mask, renormalize. In-place on A region.
// ---------------------------------------------------------------------------
__global__ void k2_softmax(float* __restrict__ A, const float* __restrict__ mask)
{
    __shared__ float sred[4];
    const int b = blockIdx.x;
    const int t = threadIdx.x;
    const int w = t >> 6;
    float* Ab = A + (size_t)b * NN;
    const float* mb = mask + (size_t)b * NN;

    float mx = -INFINITY;
    for (int i = t; i < NN; i += 256) mx = fmaxf(mx, Ab[i]);
#pragma unroll
    for (int m2 = 1; m2 < 64; m2 <<= 1) mx = fmaxf(mx, __shfl_xor(mx, m2));
    if ((t & 63) == 0) sred[w] = mx;
    __syncthreads();
    mx = fmaxf(fmaxf(sred[0], sred[1]), fmaxf(sred[2], sred[3]));
    __syncthreads();

    float se = 0.0f;
    for (int i = t; i < NN; i += 256) se += expf(Ab[i] - mx);
#pragma unroll
    for (int m2 = 1; m2 < 64; m2 <<= 1) se += __shfl_xor(se, m2);
    if ((t & 63) == 0) sred[w] = se;
    __syncthreads();
    float sum_e = sred[0] + sred[1] + sred[2] + sred[3];
    __syncthreads();

    float inv_se = 1.0f / sum_e;
    float s2 = 0.0f;
    for (int i = t; i < NN; i += 256) {
        float p = expf(Ab[i] - mx) * inv_se * mb[i];
        Ab[i] = p;
        s2 += p;
    }
#pragma unroll
    for (int m2 = 1; m2 < 64; m2 <<= 1) s2 += __shfl_xor(s2, m2);
    if ((t & 63) == 0) sred[w] = s2;
    __syncthreads();
    float S2 = sred[0] + sred[1] + sred[2] + sred[3];

    float scale = 1.0f / (S2 + EPSV);
    for (int i = t; i < NN; i += 256) Ab[i] *= scale;
}

// ---------------------------------------------------------------------------
// K3a: binary-search the k-th largest approx logit; classify into
// definite-in (> tv+DELTA, written to idxWS[0..m1)) and candidates
// (within +-DELTA, written to candIdx). counts[b*4]={m1}, [b*4+1]={candCnt}.
// ---------------------------------------------------------------------------
__global__ void k3a_band(const float* __restrict__ L, const float* __restrict__ mask,
                         const int* __restrict__ kp, int* __restrict__ idxWS,
                         int* __restrict__ candIdx, int* __restrict__ counts)
{
    __shared__ int sredi[4];
    __shared__ int sIn, sCand;
    const int b = blockIdx.x;
    const int t = threadIdx.x;
    const int w = t >> 6;
    int k = get_k(kp); if (k > KCAP) k = KCAP;
    const float* Lb = L + (size_t)b * NN;
    const float* mb = mask + (size_t)b * NN;

    float lv[64]; unsigned kk[64];
#pragma unroll
    for (int j = 0; j < 64; ++j) {
        int i = t + j * 256;
        float v = Lb[i];
        v = (mb[i] > 0.0f) ? v : -3.0e38f;
        lv[j] = v; kk[j] = okey(v);
    }

    unsigned lo = 0u, hi = 0xFFFFFFFFu;
    while (lo < hi) {
        unsigned span = hi - lo;
        unsigned mid = lo + (span >> 1) + (span & 1u);
        int c = 0;
#pragma unroll
        for (int j = 0; j < 64; ++j) c += (kk[j] >= mid) ? 1 : 0;
#pragma unroll
        for (int m2 = 1; m2 < 64; m2 <<= 1) c += __shfl_xor(c, m2);
        __syncthreads();
        if ((t & 63) == 0) sredi[w] = c;
        __syncthreads();
        c = sredi[0] + sredi[1] + sredi[2] + sredi[3];
        if (c >= k) lo = mid; else hi = mid - 1;
    }
    const float tv = inv_okey(lo);

    if (t == 0) { sIn = 0; sCand = 0; }
    __syncthreads();
    const float hiB = tv + DELTA, loB = tv - DELTA;
#pragma unroll
    for (int j = 0; j < 64; ++j) {
        int i = t + j * 256;
        float v = lv[j];
        if (v > hiB) {
            int p = atomicAdd(&sIn, 1);
            if (p < KCAP) idxWS[b * KCAP + p] = i;
        } else if (v >= loB) {
            int p = atomicAdd(&sCand, 1);
            if (p < CCAP) candIdx[b * CCAP + p] = i;
        }
    }
    __syncthreads();
    if (t == 0) {
        int m1 = sIn;  if (m1 > k)    m1 = k;
        int cc = sCand; if (cc > CCAP) cc = CCAP;
        counts[b * 4]     = m1;
        counts[b * 4 + 1] = cc;
    }
}

// ---------------------------------------------------------------------------
// K3b: exact fp32 logits for band candidates. 128 threads/block, thread = d.
// ---------------------------------------------------------------------------
__global__ void k3b_exact(const float* __restrict__ x,
                          const float* __restrict__ Wv, const float* __restrict__ bv,
                          const float* __restrict__ Wu, const float* __restrict__ bu,
                          const float* __restrict__ Wa, const float* __restrict__ ba,
                          const int* __restrict__ candIdx, const int* __restrict__ counts,
                          float* __restrict__ candVal)
{
    __shared__ float sx[LDIM];
    __shared__ float sr[2];
    const int b = blockIdx.x;
    const int t = threadIdx.x;   // 0..127
    const int cnt = counts[b * 4 + 1];
    for (int ci = blockIdx.y; ci < cnt; ci += gridDim.y) {
        const int row = candIdx[b * CCAP + ci];
        const float* xr = x + ((size_t)b * NN + (size_t)row) * LDIM;
        ((f32x4*)sx)[t] = ((const f32x4*)xr)[t];
        __syncthreads();
        float dv = bv[t], du = bu[t];
        for (int ll = 0; ll < LDIM; ++ll) {
            float xv = sx[ll];
            dv = fmaf(xv, Wv[ll * DDIM + t], dv);
            du = fmaf(xv, Wu[ll * DDIM + t], du);
        }
        float c = tanhf(dv) * (1.0f / (1.0f + expf(-du))) * Wa[t];
#pragma unroll
        for (int m2 = 1; m2 < 64; m2 <<= 1) c += __shfl_xor(c, m2);
        if ((t & 63) == 0) sr[t >> 6] = c;
        __syncthreads();
        if (t == 0) candVal[b * CCAP + ci] = sr[0] + sr[1] + ba[0];
        __syncthreads();
    }
}

// ---------------------------------------------------------------------------
// K3c: pick top (k - m1) candidates by exact logit (tie -> lowest index),
// append to idxWS, then rank-sort idxWS[b][0..k) by index (determinism).
// ---------------------------------------------------------------------------
__global__ void k3c_select(const int* __restrict__ kp, const int* __restrict__ candIdx,
                           const float* __restrict__ candVal, const int* __restrict__ counts,
                           int* __restrict__ idxWS)
{
    __shared__ unsigned long long keys[CCAP];
    __shared__ int sPos;
    __shared__ int finalIdx[KCAP];
    const int b = blockIdx.x;
    const int t = threadIdx.x;
    int k = get_k(kp); if (k > KCAP) k = KCAP;
    const int m1  = counts[b * 4];
    const int cnt = counts[b * 4 + 1];
    int need = k - m1; if (need < 0) need = 0; if (need > cnt) need = cnt;

    for (int i = t; i < cnt; i += 256)
        keys[i] = (((unsigned long long)okey(candVal[b * CCAP + i])) << 14)
                | (unsigned long long)(16383 - candIdx[b * CCAP + i]);
    if (t == 0) sPos = 0;
    __syncthreads();
    for (int i = t; i < cnt; i += 256) {
        unsigned long long mk = keys[i];
        int rank = 0;
        for (int j2 = 0; j2 < cnt; ++j2) rank += (keys[j2] > mk) ? 1 : 0;
        if (rank < need) {
            int p = atomicAdd(&sPos, 1);
            idxWS[b * KCAP + m1 + p] = candIdx[b * CCAP + i];
        }
    }
    __syncthreads();
    int tot = m1 + need; if (tot > k) tot = k;
    if (t < tot) finalIdx[t] = idxWS[b * KCAP + t];
    __syncthreads();
    if (t < tot) {
        int myv = finalIdx[t];
        int rank = 0;
        for (int e = 0; e < tot; ++e) rank += (finalIdx[e] < myv) ? 1 : 0;
        idxWS[b * KCAP + rank] = myv;
    }
    if (t >= tot && t < k) idxWS[b * KCAP + t] = 0;   // pathological pad
}

// ---------------------------------------------------------------------------
// K4: gather top-k rows of x, mean-pool, MLP, argmax. One block per batch.
// ---------------------------------------------------------------------------
__global__ void k4_final(const float* __restrict__ x, const int* __restrict__ idxws,
                         const int* __restrict__ kp,
                         const float* __restrict__ W1, const float* __restrict__ b1,
                         const float* __restrict__ W2, const float* __restrict__ b2,
                         float* __restrict__ Yprob, float* __restrict__ Yhat)
{
    __shared__ float sPooled[LDIM];
    __shared__ float sH[HIDD];
    __shared__ float sY[4];
    __shared__ int   sIdx[KCAP];
    const int b = blockIdx.x;
    const int t = threadIdx.x;
    int k = get_k(kp); if (k > KCAP) k = KCAP;

    if (t < k) sIdx[t] = idxws[b * KCAP + t];
    __syncthreads();

    float a0 = 0.0f, a1 = 0.0f;
    for (int j = 0; j < k; ++j) {
        const float* xr = x + ((size_t)b * NN + (size_t)sIdx[j]) * LDIM;
        a0 += xr[t];
        a1 += xr[t + 256];
    }
    const float invk = 1.0f / (float)k;
    sPooled[t]       = a0 * invk;
    sPooled[t + 256] = a1 * invk;
    __syncthreads();

    if (t < HIDD) {
        float acc = b1[t];
        for (int ll = 0; ll < LDIM; ++ll) acc = fmaf(sPooled[ll], W1[ll * HIDD + t], acc);
        sH[t] = fmaxf(acc, 0.0f);
    }
    __syncthreads();
    if (t < NCLS) {
        float y = b2[t];
        for (int h = 0; h < HIDD; ++h) y = fmaf(sH[h], W2[h * NCLS + t], y);
        Yprob[b * NCLS + t] = y;
        sY[t] = y;
    }
    __syncthreads();
    if (t == 0) {
        int am = 0; float bst = sY[0];
        if (sY[1] > bst) { bst = sY[1]; am = 1; }
        if (sY[2] > bst) { bst = sY[2]; am = 2; }
        Yhat[b] = (float)am;
    }
}

// ---------------------------------------------------------------------------
extern "C" void kernel_launch(void* const* d_in, const int* in_sizes, int n_in,
                              void* d_out, int out_size, void* d_ws, size_t ws_size,
                              hipStream_t stream)
{
    const float* x    = (const float*)d_in[0];
    const float* mask = (const float*)d_in[1];
    const float* Wv   = (const float*)d_in[2];
    const float* bv   = (const float*)d_in[3];
    const float* Wu   = (const float*)d_in[4];
    const float* bu   = (const float*)d_in[5];
    const float* Wa   = (const float*)d_in[6];
    const float* ba   = (const float*)d_in[7];
    const float* W1   = (const float*)d_in[8];
    const float* b1   = (const float*)d_in[9];
    const float* W2   = (const float*)d_in[10];
    const float* b2   = (const float*)d_in[11];
    const int*   kp   = (const int*)d_in[12];

    float* out   = (float*)d_out;
    float* Yprob = out;        // [16,3] = 48
    float* Yhat  = out + 48;   // [16]
    float* A     = out + 64;   // [16,16384]  (logits first, softmax in-place)

    char* wsb = (char*)d_ws;
    unsigned short* Wp = (unsigned short*)wsb;        // 262144 B
    int*   idxWS   = (int*)  (wsb + 262144);          // 16*256*4  = 16 KB
    int*   candIdx = (int*)  (wsb + 278528);          // 16*1024*4 = 64 KB
    float* candVal = (float*)(wsb + 344064);          // 64 KB
    int*   counts  = (int*)  (wsb + 409600);          // 256 B

    k0_prep  <<<512, 256, 0, stream>>>(Wv, Wu, Wp);
    k1_mfma  <<<2048, 256, 0, stream>>>(x, Wp, bv, bu, Wa, ba, A);
    k3a_band <<<NB, 256, 0, stream>>>(A, mask, kp, idxWS, candIdx, counts);
    k3b_exact<<<dim3(NB, 32), 128, 0, stream>>>(x, Wv, bv, Wu, bu, Wa, ba,
                                                candIdx, counts, candVal);
    k3c_select<<<NB, 256, 0, stream>>>(kp, candIdx, candVal, counts, idxWS);
    k2_softmax<<<NB, 256, 0, stream>>>(A, mask);
    k4_final <<<NB, 256, 0, stream>>>(x, idxWS, kp, W1, b1, W2, b2, Yprob, Yhat);
}

// Round 3
// 301.975 us; speedup vs baseline: 77.9662x; 1.5327x over previous
//
#include <hip/hip_runtime.h>
#include <math.h>

#define NB   16
#define NN   16384
#define LDIM 512
#define DDIM 128
#define HIDD 128
#define NCLS 3
#define KCAP 256
#define CCAP 1024
#define EPSV 1e-8f
#define DELTA 0.02f

typedef float  f32x4  __attribute__((ext_vector_type(4)));
typedef int    i32x4  __attribute__((ext_vector_type(4)));
typedef __bf16 bf16x8 __attribute__((ext_vector_type(8)));
typedef unsigned long long u64;

__device__ __forceinline__ int get_k(const int* kp) {
    int k = kp[0];
    if (k < 1 || k > NN) {
        float f = __int_as_float(k);
        if (f >= 1.0f && f <= (float)NN) k = (int)f;
        else k = 70;
    }
    if (k > NN) k = NN;
    return k;
}

__device__ __forceinline__ unsigned okey(float f) {
    unsigned u = __float_as_uint(f);
    return (u & 0x80000000u) ? ~u : (u | 0x80000000u);
}
__device__ __forceinline__ float inv_okey(unsigned k) {
    unsigned u = (k & 0x80000000u) ? (k & 0x7FFFFFFFu) : ~k;
    return __uint_as_float(u);
}

// pack two fp32 -> two RNE bf16 in one u32 (a -> low, b -> high)
__device__ __forceinline__ unsigned pk2bf(float a, float b) {
    unsigned ua = __float_as_uint(a); ua = (ua + 0x7FFFu + ((ua >> 16) & 1u)) >> 16;
    unsigned ub = __float_as_uint(b); ub = (ub + 0x7FFFu + ((ub >> 16) & 1u)) & 0xFFFF0000u;
    return (ua & 0xFFFFu) | ub;
}

__device__ __forceinline__ f32x4 mfma16(i32x4 a, i32x4 b, f32x4 c) {
    return __builtin_amdgcn_mfma_f32_16x16x32_bf16(
        __builtin_bit_cast(bf16x8, a), __builtin_bit_cast(bf16x8, b), c, 0, 0, 0);
}

__device__ __forceinline__ float sig_fast(float v)  { return 1.0f / (1.0f + __expf(-v)); }
__device__ __forceinline__ float tanh_fast(float v) { return 1.0f - 2.0f / (1.0f + __expf(2.0f * v)); }

// ---------------------------------------------------------------------------
// K0: swizzle Wv,Wu (fp32 [512][128]) into bf16 FRAGMENT-LANE order:
// short-idx = kt*8192 + g*4096 + nt*512 + lg*128 + lr*8 + j
//   (kt=k/32, lg=(k/8)%4, j=k%8, nt=n/16, lr=n%16) — so a B-frag for
//   (g,nt) is one contiguous 16B chunk per lane l = lg*16+lr.
// ---------------------------------------------------------------------------
__global__ void k0_prep(const float* __restrict__ Wv, const float* __restrict__ Wu,
                        unsigned short* __restrict__ Wp)
{
    int i = blockIdx.x * 256 + threadIdx.x;    // 0 .. 131071
    int g   = i >> 16;
    int rem = i & 65535;                       // kd*128 + n
    int kd  = rem >> 7;
    int n   = rem & 127;
    float w = g ? Wu[rem] : Wv[rem];
    unsigned u = __float_as_uint(w);
    u = (u + 0x7FFFu + ((u >> 16) & 1u)) >> 16;
    int kt = kd >> 5, lg = (kd >> 3) & 3, j = kd & 7, nt = n >> 4, lr = n & 15;
    Wp[kt * 8192 + g * 4096 + nt * 512 + lg * 128 + lr * 8 + j] = (unsigned short)u;
}

// ---------------------------------------------------------------------------
// K1: fused gated-attention logits via bf16 MFMA, LDS-staged.
// Block 256 thr = 4 waves, BM=128 rows; wave owns 32 rows x 128 cols x 2 gates.
// LDS: X double-buffer 2x8KB (bf16, chunk-XOR swizzle), B double-buffer 2x16KB
// (linear frag-order copy of Wp's kt-slice, shared by the 4 waves).
// One __syncthreads per K-step: writes(buf p) -> barrier -> reads(buf p).
// ---------------------------------------------------------------------------
__global__ __launch_bounds__(256, 2)
void k1_mfma(const float* __restrict__ x, const unsigned short* __restrict__ Wp,
             const float* __restrict__ bv, const float* __restrict__ bu,
             const float* __restrict__ Wa, const float* __restrict__ ba,
             float* __restrict__ logits)
{
    __shared__ __align__(16) char lds[49152];  // X0 X1 (8KB ea) | B0 B1 (16KB ea)

    const int t   = threadIdx.x;
    const int wid = t >> 6;
    const int l   = t & 63;
    const int lr  = l & 15;
    const int lg  = l >> 4;
    const int row0  = blockIdx.x * 128;
    const int row0w = row0 + wid * 32;

    // staging roles: thread t stages x row (t>>1), half h=(t&1) (16 floats)
    const int srow = t >> 1;
    const int sh   = t & 1;
    const float* xsrc = x + (size_t)(row0 + srow) * LDIM + sh * 16;
    const int sswz = (srow >> 1) & 3;
    char* xw0 = lds + srow * 64 + (((sh * 2 + 0) ^ sswz) * 16);
    char* xw1 = lds + srow * 64 + (((sh * 2 + 1) ^ sswz) * 16);
    const unsigned short* bsrc = Wp + t * 8;   // + q*2048 shorts, + kt*8192 shorts
    char* bw = lds + 16384 + t * 16;           // + q*4096 bytes

    f32x4 acc[2][2][8];
#pragma unroll
    for (int g = 0; g < 2; ++g)
#pragma unroll
        for (int rt = 0; rt < 2; ++rt)
#pragma unroll
            for (int nt = 0; nt < 8; ++nt)
                acc[g][rt][nt] = f32x4{0.f, 0.f, 0.f, 0.f};

    // prologue: global loads for kt=0
    f32x4 xg[4]; i32x4 bg[4];
#pragma unroll
    for (int q = 0; q < 4; ++q) xg[q] = ((const f32x4*)xsrc)[q];
#pragma unroll
    for (int q = 0; q < 4; ++q) bg[q] = *(const i32x4*)(bsrc + q * 2048);

    // per-lane frag read offsets (constant)
    const int fswz = (lg ^ ((lr >> 1) & 3)) * 16;
    const int xr0  = (wid * 32 + lr) * 64 + fswz;
    const int xr1  = (wid * 32 + 16 + lr) * 64 + fswz;

#pragma unroll 2
    for (int kt = 0; kt < 16; ++kt) {
        const int p = kt & 1;
        // (1) pack + LDS writes for tile kt
        i32x4 wv0, wv1;
        wv0.x = pk2bf(xg[0].x, xg[0].y); wv0.y = pk2bf(xg[0].z, xg[0].w);
        wv0.z = pk2bf(xg[1].x, xg[1].y); wv0.w = pk2bf(xg[1].z, xg[1].w);
        wv1.x = pk2bf(xg[2].x, xg[2].y); wv1.y = pk2bf(xg[2].z, xg[2].w);
        wv1.z = pk2bf(xg[3].x, xg[3].y); wv1.w = pk2bf(xg[3].z, xg[3].w);
        *(i32x4*)(xw0 + p * 8192) = wv0;
        *(i32x4*)(xw1 + p * 8192) = wv1;
#pragma unroll
        for (int q = 0; q < 4; ++q) *(i32x4*)(bw + p * 16384 + q * 4096) = bg[q];
        // (2) issue next tile's global loads (fly across barrier + MFMA)
        if (kt < 15) {
            const float* xs = xsrc + (size_t)(kt + 1) * 32;
#pragma unroll
            for (int q = 0; q < 4; ++q) xg[q] = ((const f32x4*)xs)[q];
            const unsigned short* bs = bsrc + (size_t)(kt + 1) * 8192;
#pragma unroll
            for (int q = 0; q < 4; ++q) bg[q] = *(const i32x4*)(bs + q * 2048);
        }
        __syncthreads();
        // (3) frag reads + MFMA
        const char* Xb = lds + p * 8192;
        const char* Bb = lds + 16384 + p * 16384;
        i32x4 a0 = *(const i32x4*)(Xb + xr0);
        i32x4 a1 = *(const i32x4*)(Xb + xr1);
#pragma unroll
        for (int g = 0; g < 2; ++g) {
#pragma unroll
            for (int nt = 0; nt < 8; ++nt) {
                i32x4 bf = *(const i32x4*)(Bb + g * 8192 + nt * 1024 + l * 16);
                acc[g][0][nt] = mfma16(a0, bf, acc[g][0][nt]);
                acc[g][1][nt] = mfma16(a1, bf, acc[g][1][nt]);
            }
        }
    }

    // epilogue: tanh(V+bv)*sigmoid(U+bu)*Wa, reduce over 128 cols (verified r2)
    float bvc[8], buc[8], wac[8];
#pragma unroll
    for (int nt = 0; nt < 8; ++nt) {
        int col = nt * 16 + lr;
        bvc[nt] = bv[col]; buc[nt] = bu[col]; wac[nt] = Wa[col];
    }
    const float ba0 = ba[0];
#pragma unroll
    for (int rt = 0; rt < 2; ++rt) {
#pragma unroll
        for (int r = 0; r < 4; ++r) {
            float s = 0.f;
#pragma unroll
            for (int nt = 0; nt < 8; ++nt) {
                float vv = tanh_fast(acc[0][rt][nt][r] + bvc[nt]);
                float uu = sig_fast (acc[1][rt][nt][r] + buc[nt]);
                s = fmaf(vv * uu, wac[nt], s);
            }
            s += __shfl_xor(s, 1); s += __shfl_xor(s, 2);
            s += __shfl_xor(s, 4); s += __shfl_xor(s, 8);
            if (lr == 0)
                logits[row0w + rt * 16 + lg * 4 + r] = s + ba0;
        }
    }
}

// ---------------------------------------------------------------------------
// K3a: fused band-classify + softmax. Per batch: binary-search k-th largest
// masked logit, classify definite-in / band candidates, then write the final
// masked-renormalized softmax in one pass (denominators cancel:
// A_i = mask_i*e^{l_i-M} / (S_masked + EPS*S_all)).
// ---------------------------------------------------------------------------
__global__ void k3a_band_softmax(float* __restrict__ A, const float* __restrict__ mask,
                                 const int* __restrict__ kp, int* __restrict__ idxWS,
                                 int* __restrict__ candIdx, int* __restrict__ counts)
{
    __shared__ float sredf[4];
    __shared__ int sredi[4];
    __shared__ int sIn, sCand;
    const int b = blockIdx.x;
    const int t = threadIdx.x;
    const int w = t >> 6;
    int k = get_k(kp); if (k > KCAP) k = KCAP;
    float* Ab = A + (size_t)b * NN;
    const float* mb = mask + (size_t)b * NN;

    float raw[64]; u64 mbits = 0ULL;
#pragma unroll
    for (int j = 0; j < 64; ++j) {
        int i = t + j * 256;
        raw[j] = Ab[i];
        if (mb[i] > 0.0f) mbits |= (1ULL << j);
    }
    unsigned kk[64];
#pragma unroll
    for (int j = 0; j < 64; ++j) {
        float v = ((mbits >> j) & 1) ? raw[j] : -3.0e38f;
        kk[j] = okey(v);
    }
    // binary search: largest T with count(key >= T) >= k
    unsigned lo = 0u, hi = 0xFFFFFFFFu;
    while (lo < hi) {
        unsigned span = hi - lo;
        unsigned mid = lo + (span >> 1) + (span & 1u);
        int c = 0;
#pragma unroll
        for (int j = 0; j < 64; ++j) c += (kk[j] >= mid) ? 1 : 0;
#pragma unroll
        for (int m2 = 1; m2 < 64; m2 <<= 1) c += __shfl_xor(c, m2);
        __syncthreads();
        if ((t & 63) == 0) sredi[w] = c;
        __syncthreads();
        c = sredi[0] + sredi[1] + sredi[2] + sredi[3];
        if (c >= k) lo = mid; else hi = mid - 1;
    }
    const float tv = inv_okey(lo);

    if (t == 0) { sIn = 0; sCand = 0; }
    __syncthreads();
    const float hiB = tv + DELTA, loB = tv - DELTA;
#pragma unroll
    for (int j = 0; j < 64; ++j) {
        int i = t + j * 256;
        float v = ((mbits >> j) & 1) ? raw[j] : -3.0e38f;
        if (v > hiB)       { int p = atomicAdd(&sIn, 1);   if (p < KCAP) idxWS[b * KCAP + p] = i; }
        else if (v >= loB) { int p = atomicAdd(&sCand, 1); if (p < CCAP) candIdx[b * CCAP + p] = i; }
    }

    // fused softmax: M = unmasked max (matches reference softmax axis=1)
    float mx = -INFINITY;
#pragma unroll
    for (int j = 0; j < 64; ++j) mx = fmaxf(mx, raw[j]);
#pragma unroll
    for (int m2 = 1; m2 < 64; m2 <<= 1) mx = fmaxf(mx, __shfl_xor(mx, m2));
    __syncthreads();
    if ((t & 63) == 0) sredf[w] = mx;
    __syncthreads();
    mx = fmaxf(fmaxf(sredf[0], sredf[1]), fmaxf(sredf[2], sredf[3]));

    float sAll = 0.f, sM = 0.f;
#pragma unroll
    for (int j = 0; j < 64; ++j) {
        float e = __expf(raw[j] - mx);
        sAll += e;
        if ((mbits >> j) & 1) sM += e;
    }
#pragma unroll
    for (int m2 = 1; m2 < 64; m2 <<= 1) sAll += __shfl_xor(sAll, m2);
    __syncthreads();
    if ((t & 63) == 0) sredf[w] = sAll;
    __syncthreads();
    sAll = sredf[0] + sredf[1] + sredf[2] + sredf[3];
#pragma unroll
    for (int m2 = 1; m2 < 64; m2 <<= 1) sM += __shfl_xor(sM, m2);
    __syncthreads();
    if ((t & 63) == 0) sredf[w] = sM;
    __syncthreads();
    sM = sredf[0] + sredf[1] + sredf[2] + sredf[3];

    const float inv = 1.0f / (sM + EPSV * sAll);
#pragma unroll
    for (int j = 0; j < 64; ++j) {
        int i = t + j * 256;
        float e = __expf(raw[j] - mx);
        Ab[i] = ((mbits >> j) & 1) ? e * inv : 0.0f;
    }
    if (t == 0) {
        int m1 = sIn;   if (m1 > k)    m1 = k;
        int cc = sCand; if (cc > CCAP) cc = CCAP;
        counts[b * 4]     = m1;
        counts[b * 4 + 1] = cc;
    }
}

// ---------------------------------------------------------------------------
// K3b: exact fp32 logits for band candidates (resolves bf16 ranking ambiguity).
// ---------------------------------------------------------------------------
__global__ void k3b_exact(const float* __restrict__ x,
                          const float* __restrict__ Wv, const float* __restrict__ bv,
                          const float* __restrict__ Wu, const float* __restrict__ bu,
                          const float* __restrict__ Wa, const float* __restrict__ ba,
                          const int* __restrict__ candIdx, const int* __restrict__ counts,
                          float* __restrict__ candVal)
{
    __shared__ float sx[LDIM];
    __shared__ float sr[2];
    const int b = blockIdx.x;
    const int t = threadIdx.x;   // 0..127
    const int cnt = counts[b * 4 + 1];
    for (int ci = blockIdx.y; ci < cnt; ci += gridDim.y) {
        const int row = candIdx[b * CCAP + ci];
        const float* xr = x + ((size_t)b * NN + (size_t)row) * LDIM;
        ((f32x4*)sx)[t] = ((const f32x4*)xr)[t];
        __syncthreads();
        float dv = bv[t], du = bu[t];
        for (int ll = 0; ll < LDIM; ++ll) {
            float xv = sx[ll];
            dv = fmaf(xv, Wv[ll * DDIM + t], dv);
            du = fmaf(xv, Wu[ll * DDIM + t], du);
        }
        float c = tanhf(dv) * (1.0f / (1.0f + expf(-du))) * Wa[t];
#pragma unroll
        for (int m2 = 1; m2 < 64; m2 <<= 1) c += __shfl_xor(c, m2);
        if ((t & 63) == 0) sr[t >> 6] = c;
        __syncthreads();
        if (t == 0) candVal[b * CCAP + ci] = sr[0] + sr[1] + ba[0];
        __syncthreads();
    }
}

// ---------------------------------------------------------------------------
// K34: select top (k-m1) candidates by exact logit (tie -> lowest index),
// rank-sort final index set, then gather+mean-pool+MLP+argmax. One blk/batch.
// ---------------------------------------------------------------------------
__global__ void k34_select_final(const float* __restrict__ x, const int* __restrict__ kp,
                                 const int* __restrict__ candIdx, const float* __restrict__ candVal,
                                 const int* __restrict__ counts, const int* __restrict__ idxWS,
                                 const float* __restrict__ W1, const float* __restrict__ b1,
                                 const float* __restrict__ W2, const float* __restrict__ b2,
                                 float* __restrict__ Yprob, float* __restrict__ Yhat)
{
    __shared__ u64 keys[CCAP];
    __shared__ int sIdx[KCAP];
    __shared__ int sFinal[KCAP];
    __shared__ int sPos;
    __shared__ float sPooled[LDIM];
    __shared__ float sH[HIDD];
    __shared__ float sY[4];
    const int b = blockIdx.x;
    const int t = threadIdx.x;
    int k = get_k(kp); if (k > KCAP) k = KCAP;
    const int m1  = counts[b * 4];
    const int cnt = counts[b * 4 + 1];
    int need = k - m1; if (need < 0) need = 0; if (need > cnt) need = cnt;

    for (int i = t; i < cnt; i += 256)
        keys[i] = (((u64)okey(candVal[b * CCAP + i])) << 14)
                | (u64)(16383 - candIdx[b * CCAP + i]);
    if (t < m1) sIdx[t] = idxWS[b * KCAP + t];
    if (t == 0) sPos = 0;
    if (t < KCAP) sFinal[t] = 0;
    __syncthreads();
    for (int i = t; i < cnt; i += 256) {
        u64 mk = keys[i];
        int rank = 0;
        for (int j = 0; j < cnt; ++j) rank += (keys[j] > mk) ? 1 : 0;
        if (rank < need) { int p = atomicAdd(&sPos, 1); sIdx[m1 + p] = candIdx[b * CCAP + i]; }
    }
    __syncthreads();
    int tot = m1 + need; if (tot > k) tot = k;
    if (t < tot) {
        int myv = sIdx[t];
        int rank = 0;
        for (int e = 0; e < tot; ++e) rank += (sIdx[e] < myv) ? 1 : 0;
        sFinal[rank] = myv;
    }
    __syncthreads();

    float a0 = 0.0f, a1 = 0.0f;
    for (int j = 0; j < k; ++j) {
        const float* xr = x + ((size_t)b * NN + (size_t)sFinal[j]) * LDIM;
        a0 += xr[t];
        a1 += xr[t + 256];
    }
    const float invk = 1.0f / (float)k;
    sPooled[t]       = a0 * invk;
    sPooled[t + 256] = a1 * invk;
    __syncthreads();

    if (t < HIDD) {
        float acc = b1[t];
        for (int ll = 0; ll < LDIM; ++ll) acc = fmaf(sPooled[ll], W1[ll * HIDD + t], acc);
        sH[t] = fmaxf(acc, 0.0f);
    }
    __syncthreads();
    if (t < NCLS) {
        float y = b2[t];
        for (int h = 0; h < HIDD; ++h) y = fmaf(sH[h], W2[h * NCLS + t], y);
        Yprob[b * NCLS + t] = y;
        sY[t] = y;
    }
    __syncthreads();
    if (t == 0) {
        int am = 0; float bst = sY[0];
        if (sY[1] > bst) { bst = sY[1]; am = 1; }
        if (sY[2] > bst) { bst = sY[2]; am = 2; }
        Yhat[b] = (float)am;
    }
}

// ---------------------------------------------------------------------------
extern "C" void kernel_launch(void* const* d_in, const int* in_sizes, int n_in,
                              void* d_out, int out_size, void* d_ws, size_t ws_size,
                              hipStream_t stream)
{
    const float* x    = (const float*)d_in[0];
    const float* mask = (const float*)d_in[1];
    const float* Wv   = (const float*)d_in[2];
    const float* bv   = (const float*)d_in[3];
    const float* Wu   = (const float*)d_in[4];
    const float* bu   = (const float*)d_in[5];
    const float* Wa   = (const float*)d_in[6];
    const float* ba   = (const float*)d_in[7];
    const float* W1   = (const float*)d_in[8];
    const float* b1   = (const float*)d_in[9];
    const float* W2   = (const float*)d_in[10];
    const float* b2   = (const float*)d_in[11];
    const int*   kp   = (const int*)d_in[12];

    float* out   = (float*)d_out;
    float* Yprob = out;        // [16,3] = 48
    float* Yhat  = out + 48;   // [16]
    float* A     = out + 64;   // [16,16384]  (logits first, softmax in-place)

    char* wsb = (char*)d_ws;
    unsigned short* Wp = (unsigned short*)wsb;        // 262144 B
    int*   idxWS   = (int*)  (wsb + 262144);          // 16 KB
    int*   candIdx = (int*)  (wsb + 278528);          // 64 KB
    float* candVal = (float*)(wsb + 344064);          // 64 KB
    int*   counts  = (int*)  (wsb + 409600);          // 256 B

    k0_prep  <<<512, 256, 0, stream>>>(Wv, Wu, Wp);
    k1_mfma  <<<2048, 256, 0, stream>>>(x, Wp, bv, bu, Wa, ba, A);
    k3a_band_softmax<<<NB, 256, 0, stream>>>(A, mask, kp, idxWS, candIdx, counts);
    k3b_exact<<<dim3(NB, 32), 128, 0, stream>>>(x, Wv, bv, Wu, bu, Wa, ba,
                                                candIdx, counts, candVal);
    k34_select_final<<<NB, 256, 0, stream>>>(x, kp, candIdx, candVal, counts, idxWS,
                                             W1, b1, W2, b2, Yprob, Yhat);
}